// Round 1
// baseline (118.289 us; speedup 1.0000x reference)
//
#include <hip/hip_runtime.h>

// RBF interpolation onto a 128x128 grid.
// x_c: (B, NC, 2) f32, y_c: (B, NC, 8) f32, grid: (1, M, 2) f32, sigma scalar.
// out: (B, 9, M) f32  [channel 0 = density, 1..8 = signal/(density+1e-5)]

constexpr int B_  = 8;
constexpr int NC  = 2048;
constexpr int YD  = 8;
constexpr int M_  = 128 * 128;
constexpr int NT  = 1024;                 // n-tile staged in LDS (40 KiB)
constexpr int BLK = 256;                  // threads per block
constexpr int PTS = 2;                    // grid points per thread
constexpr int PTS_PER_BLOCK    = BLK * PTS;          // 512
constexpr int BLOCKS_PER_BATCH = M_ / PTS_PER_BLOCK; // 32

__global__ __launch_bounds__(BLK) void rbf_kernel(
    const float* __restrict__ x_c,
    const float* __restrict__ y_c,
    const float* __restrict__ gp,
    const float* __restrict__ sigma_p,
    float* __restrict__ out)
{
    __shared__ float2 sx[NT];          // 8 KiB
    __shared__ float4 sy[NT * 2];      // 32 KiB

    const int b     = blockIdx.x / BLOCKS_PER_BATCH;
    const int mbase = (blockIdx.x % BLOCKS_PER_BATCH) * PTS_PER_BLOCK;
    const int m0    = mbase + (int)threadIdx.x;
    const int m1    = m0 + BLK;

    const float sigma = sigma_p[0];
    // w = exp(-0.5*d2/sigma^2) = 2^(d2 * (-0.5*log2e/sigma^2))
    const float scale = -0.72134752044448170f / (sigma * sigma);

    const float2 g0 = ((const float2*)gp)[m0];
    const float2 g1 = ((const float2*)gp)[m1];

    float den0 = 0.0f, den1 = 0.0f;
    float acc0[YD], acc1[YD];
#pragma unroll
    for (int y = 0; y < YD; ++y) { acc0[y] = 0.0f; acc1[y] = 0.0f; }

    const float2* xb = (const float2*)x_c + (size_t)b * NC;
    const float4* yb = (const float4*)y_c + (size_t)b * NC * 2;

    for (int t0 = 0; t0 < NC; t0 += NT) {
        __syncthreads();
        for (int i = (int)threadIdx.x; i < NT; i += BLK)
            sx[i] = xb[t0 + i];
        for (int i = (int)threadIdx.x; i < NT * 2; i += BLK)
            sy[i] = yb[(size_t)t0 * 2 + i];
        __syncthreads();

#pragma unroll 4
        for (int n = 0; n < NT; ++n) {
            const float2 xn = sx[n];
            const float4 ya = sy[2 * n];
            const float4 yc4 = sy[2 * n + 1];

            const float dx0 = xn.x - g0.x, dy0 = xn.y - g0.y;
            const float dx1 = xn.x - g1.x, dy1 = xn.y - g1.y;
            const float d20 = dx0 * dx0 + dy0 * dy0;
            const float d21 = dx1 * dx1 + dy1 * dy1;
            const float w0 = __builtin_amdgcn_exp2f(d20 * scale);
            const float w1 = __builtin_amdgcn_exp2f(d21 * scale);

            den0 += w0; den1 += w1;
            acc0[0] += w0 * ya.x;  acc1[0] += w1 * ya.x;
            acc0[1] += w0 * ya.y;  acc1[1] += w1 * ya.y;
            acc0[2] += w0 * ya.z;  acc1[2] += w1 * ya.z;
            acc0[3] += w0 * ya.w;  acc1[3] += w1 * ya.w;
            acc0[4] += w0 * yc4.x; acc1[4] += w1 * yc4.x;
            acc0[5] += w0 * yc4.y; acc1[5] += w1 * yc4.y;
            acc0[6] += w0 * yc4.z; acc1[6] += w1 * yc4.z;
            acc0[7] += w0 * yc4.w; acc1[7] += w1 * yc4.w;
        }
    }

    const float inv0 = 1.0f / (den0 + 1e-5f);
    const float inv1 = 1.0f / (den1 + 1e-5f);
    float* ob = out + (size_t)b * (1 + YD) * M_;
    ob[m0] = den0;
    ob[m1] = den1;
#pragma unroll
    for (int y = 0; y < YD; ++y) {
        ob[(size_t)(y + 1) * M_ + m0] = acc0[y] * inv0;
        ob[(size_t)(y + 1) * M_ + m1] = acc1[y] * inv1;
    }
}

extern "C" void kernel_launch(void* const* d_in, const int* in_sizes, int n_in,
                              void* d_out, int out_size, void* d_ws, size_t ws_size,
                              hipStream_t stream) {
    const float* x_c   = (const float*)d_in[0];
    const float* y_c   = (const float*)d_in[1];
    const float* gp    = (const float*)d_in[2];
    const float* sigma = (const float*)d_in[3];
    float* out = (float*)d_out;

    dim3 grid(B_ * BLOCKS_PER_BATCH);   // 256 blocks
    dim3 block(BLK);
    rbf_kernel<<<grid, block, 0, stream>>>(x_c, y_c, gp, sigma, out);
}

// Round 2
// 102.822 us; speedup vs baseline: 1.1504x; 1.1504x over previous
//
#include <hip/hip_runtime.h>

// RBF interpolation onto a 128x128 grid — packed-fp32 + N-split version.
// x_c: (B, NC, 2) f32, y_c: (B, NC, 8) f32, grid: (1, M, 2) f32, sigma scalar.
// out: (B, 9, M) f32  [channel 0 = density, 1..8 = signal/(density+1e-5)]

typedef float vf2 __attribute__((ext_vector_type(2)));

constexpr int B_  = 8;
constexpr int NC  = 2048;
constexpr int YD  = 8;
constexpr int M_  = 128 * 128;
constexpr int NT  = 512;                  // n-tile staged in LDS (20 KiB)
constexpr int BLK = 256;                  // threads per block
constexpr int PTS = 2;                    // grid points per thread (packed as float2)
constexpr int NSPLIT = 2;                 // N split across blocks (bitwise-deterministic: a+b==b+a)
constexpr int PTS_PER_BLOCK  = BLK * PTS;            // 512
constexpr int MBLOCKS        = M_ / PTS_PER_BLOCK;   // 32
constexpr int BLOCKS_PER_B   = MBLOCKS * NSPLIT;     // 64
constexpr int NC_PER_SPLIT   = NC / NSPLIT;          // 1024

__global__ __launch_bounds__(BLK) void rbf_partial(
    const float* __restrict__ x_c,
    const float* __restrict__ y_c,
    const float* __restrict__ gp,
    const float* __restrict__ sigma_p,
    float* __restrict__ out)
{
    __shared__ vf2   sxs[NT];        // pre-scaled x tile, 4 KiB
    __shared__ float4 sy[NT * 2];    // y tile, 16 KiB

    const int bid   = blockIdx.x;
    const int b     = bid / BLOCKS_PER_B;
    const int r     = bid % BLOCKS_PER_B;
    const int split = r / MBLOCKS;
    const int mblk  = r % MBLOCKS;

    const int m0 = mblk * PTS_PER_BLOCK + (int)threadIdx.x;
    const int m1 = m0 + BLK;

    const float sigma = sigma_p[0];
    // w = exp(-0.5*d2/sigma^2) = exp2(-(s*dx)^2 - (s*dy)^2), s = sqrt(0.5*log2e)/sigma
    const float s = __builtin_sqrtf(0.72134752044448170f) / sigma;

    const float2 g0 = ((const float2*)gp)[m0];
    const float2 g1 = ((const float2*)gp)[m1];
    const vf2 gx = (vf2){g0.x, g1.x} * s;
    const vf2 gy = (vf2){g0.y, g1.y} * s;

    vf2 den = (vf2)0.0f;
    vf2 acc[YD];
#pragma unroll
    for (int y = 0; y < YD; ++y) acc[y] = (vf2)0.0f;

    const float2* xb = (const float2*)x_c + (size_t)b * NC;
    const float4* yb = (const float4*)y_c + (size_t)b * NC * 2;
    const int n0 = split * NC_PER_SPLIT;

    for (int t0 = n0; t0 < n0 + NC_PER_SPLIT; t0 += NT) {
        __syncthreads();
        for (int i = (int)threadIdx.x; i < NT; i += BLK) {
            const float2 xv = xb[t0 + i];
            sxs[i] = (vf2){xv.x, xv.y} * s;
        }
        for (int i = (int)threadIdx.x; i < NT * 2; i += BLK)
            sy[i] = yb[(size_t)t0 * 2 + i];
        __syncthreads();

#pragma unroll 4
        for (int n = 0; n < NT; ++n) {
            const vf2 xn  = sxs[n];
            const float4 ya  = sy[2 * n];
            const float4 yc4 = sy[2 * n + 1];

            const vf2 dx = xn.x - gx;                       // pk_sub (broadcast xn.x)
            const vf2 dy = xn.y - gy;                       // pk_sub
            const vf2 d2 = __builtin_elementwise_fma(dx, dx, dy * dy); // pk_mul + pk_fma

            vf2 w;
            w.x = __builtin_amdgcn_exp2f(-d2.x);            // trans with neg src-mod
            w.y = __builtin_amdgcn_exp2f(-d2.y);

            den += w;                                       // pk_add
            acc[0] = __builtin_elementwise_fma(w, (vf2)ya.x,  acc[0]);
            acc[1] = __builtin_elementwise_fma(w, (vf2)ya.y,  acc[1]);
            acc[2] = __builtin_elementwise_fma(w, (vf2)ya.z,  acc[2]);
            acc[3] = __builtin_elementwise_fma(w, (vf2)ya.w,  acc[3]);
            acc[4] = __builtin_elementwise_fma(w, (vf2)yc4.x, acc[4]);
            acc[5] = __builtin_elementwise_fma(w, (vf2)yc4.y, acc[5]);
            acc[6] = __builtin_elementwise_fma(w, (vf2)yc4.z, acc[6]);
            acc[7] = __builtin_elementwise_fma(w, (vf2)yc4.w, acc[7]);
        }
    }

    float* ob = out + (size_t)b * (1 + YD) * M_;
    atomicAdd(&ob[m0], den.x);
    atomicAdd(&ob[m1], den.y);
#pragma unroll
    for (int y = 0; y < YD; ++y) {
        atomicAdd(&ob[(size_t)(y + 1) * M_ + m0], acc[y].x);
        atomicAdd(&ob[(size_t)(y + 1) * M_ + m1], acc[y].y);
    }
}

__global__ __launch_bounds__(BLK) void rbf_normalize(float* __restrict__ out)
{
    const int t = blockIdx.x * BLK + (int)threadIdx.x;   // B*M threads
    const int b = t / M_;
    const int m = t % M_;
    float* ob = out + (size_t)b * (1 + YD) * M_;
    const float inv = 1.0f / (ob[m] + 1e-5f);
#pragma unroll
    for (int y = 0; y < YD; ++y)
        ob[(size_t)(y + 1) * M_ + m] *= inv;
}

extern "C" void kernel_launch(void* const* d_in, const int* in_sizes, int n_in,
                              void* d_out, int out_size, void* d_ws, size_t ws_size,
                              hipStream_t stream) {
    const float* x_c   = (const float*)d_in[0];
    const float* y_c   = (const float*)d_in[1];
    const float* gp    = (const float*)d_in[2];
    const float* sigma = (const float*)d_in[3];
    float* out = (float*)d_out;

    hipMemsetAsync(out, 0, (size_t)out_size * sizeof(float), stream);

    dim3 block(BLK);
    dim3 grid1(B_ * BLOCKS_PER_B);          // 512 blocks
    rbf_partial<<<grid1, block, 0, stream>>>(x_c, y_c, gp, sigma, out);

    dim3 grid2((B_ * M_) / BLK);            // 512 blocks
    rbf_normalize<<<grid2, block, 0, stream>>>(out);
}

// Round 4
// 52.308 us; speedup vs baseline: 2.2614x; 1.9657x over previous
//
#include <hip/hip_runtime.h>

// RBF interpolation via MFMA: D[m][ch] = sum_n w(m,n) * Y[n][ch]
// with Y[n][0] = 1 (density), Y[n][1..8] = y_c[n], ch 9..15 = 0 (padding).
// w(m,n) = exp2(-(s*dx)^2 - (s*dy)^2), s = sqrt(0.5*log2e)/sigma.

typedef float  vf2   __attribute__((ext_vector_type(2)));
typedef float  f32x4 __attribute__((ext_vector_type(4)));
typedef __fp16 half8  __attribute__((ext_vector_type(8)));
typedef __fp16 half2t __attribute__((ext_vector_type(2)));

constexpr int B_  = 8;
constexpr int NC  = 2048;
constexpr int M_  = 128 * 128;
constexpr int NT  = 512;            // n-tile staged in LDS
constexpr int NTP = 520;            // padded f16 row (stride 1040 B)
constexpr int BLK = 256;            // 4 waves
constexpr int WM  = 2;              // m-tiles (of 16) per wave
constexpr int TILES_PER_BLOCK = 4 * WM;                 // 8 tiles = 128 grid pts / block
constexpr int MBLOCKS = M_ / (TILES_PER_BLOCK * 16);    // 128
// grid = B_ * MBLOCKS = 1024 blocks

__global__ __launch_bounds__(BLK) void rbf_mfma(
    const float* __restrict__ x_c,
    const float* __restrict__ y_c,
    const float* __restrict__ gp,
    const float* __restrict__ sigma_p,
    float* __restrict__ out)
{
    __shared__ __align__(16) float xs_x[NT];
    __shared__ __align__(16) float xs_y[NT];
    __shared__ __align__(16) __fp16 sy[16 * NTP];   // [ch][n] f16

    const int tid  = (int)threadIdx.x;
    const int lane = tid & 63;
    const int w    = tid >> 6;        // wave id 0..3
    const int q    = lane >> 4;       // quarter 0..3
    const int ch   = lane & 15;       // B-col / D-col

    const int b      = blockIdx.x / MBLOCKS;
    const int mb     = blockIdx.x % MBLOCKS;
    const int m_base = mb * (TILES_PER_BLOCK * 16);

    const float sigma = sigma_p[0];
    const float s = __builtin_sqrtf(0.72134752044448170f) / sigma;

    // constant B rows: ch 0 = 1.0 (density), ch 9..15 = 0
    for (int i = tid; i < NTP; i += BLK) sy[i] = (__fp16)1.0f;
    for (int r = 9; r < 16; ++r)
        for (int i = tid; i < NTP; i += BLK) sy[r * NTP + i] = (__fp16)0.0f;

    // per-wave grid points (A rows): row = l&15
    vf2 gxv[WM], gyv[WM];
#pragma unroll
    for (int i = 0; i < WM; ++i) {
        const int mg = m_base + (w * WM + i) * 16 + ch;
        const float2 g = ((const float2*)gp)[mg];
        gxv[i] = (vf2)(g.x * s);
        gyv[i] = (vf2)(g.y * s);
    }

    f32x4 acc[WM];
#pragma unroll
    for (int i = 0; i < WM; ++i) acc[i] = (f32x4)0.0f;

    const float2* xb = (const float2*)x_c + (size_t)b * NC;
    const float2* yb = (const float2*)y_c + (size_t)b * NC * 4;

    for (int t0 = 0; t0 < NC; t0 += NT) {
        __syncthreads();
        // stage x (pre-scaled, SoA)
        for (int i = tid; i < NT; i += BLK) {
            const float2 v = xb[t0 + i];
            xs_x[i] = v.x * s;
            xs_y[i] = v.y * s;
        }
        // stage y as f16 [ch][n]; y channel j -> B row j+1
        for (int i = tid; i < NT * 4; i += BLK) {
            const int n = i >> 2, c = i & 3;
            const float2 v = yb[(size_t)(t0 + n) * 4 + c];
            const half2t h = __builtin_amdgcn_cvt_pkrtz(v.x, v.y);
            sy[(2 * c + 1) * NTP + n] = h.x;
            sy[(2 * c + 2) * NTP + n] = h.y;
        }
        __syncthreads();

        const __fp16* brow = sy + ch * NTP;

#pragma unroll 2
        for (int ks = 0; ks < NT; ks += 32) {
            const int kq = ks + q * 8;   // this lane's 8 k's
            const f32x4 xx0 = *(const f32x4*)(xs_x + kq);
            const f32x4 xx1 = *(const f32x4*)(xs_x + kq + 4);
            const f32x4 yy0 = *(const f32x4*)(xs_y + kq);
            const f32x4 yy1 = *(const f32x4*)(xs_y + kq + 4);
            const half8 bfrag = *(const half8*)(brow + kq);

#pragma unroll
            for (int i = 0; i < WM; ++i) {
                const vf2 dx0 = (vf2){xx0.x, xx0.y} - gxv[i];
                const vf2 dy0 = (vf2){yy0.x, yy0.y} - gyv[i];
                const vf2 dx1 = (vf2){xx0.z, xx0.w} - gxv[i];
                const vf2 dy1 = (vf2){yy0.z, yy0.w} - gyv[i];
                const vf2 dx2 = (vf2){xx1.x, xx1.y} - gxv[i];
                const vf2 dy2 = (vf2){yy1.x, yy1.y} - gyv[i];
                const vf2 dx3 = (vf2){xx1.z, xx1.w} - gxv[i];
                const vf2 dy3 = (vf2){yy1.z, yy1.w} - gyv[i];
                const vf2 d0 = __builtin_elementwise_fma(dx0, dx0, dy0 * dy0);
                const vf2 d1 = __builtin_elementwise_fma(dx1, dx1, dy1 * dy1);
                const vf2 d2 = __builtin_elementwise_fma(dx2, dx2, dy2 * dy2);
                const vf2 d3 = __builtin_elementwise_fma(dx3, dx3, dy3 * dy3);
                const half2t w0 = __builtin_amdgcn_cvt_pkrtz(
                    __builtin_amdgcn_exp2f(-d0.x), __builtin_amdgcn_exp2f(-d0.y));
                const half2t w1 = __builtin_amdgcn_cvt_pkrtz(
                    __builtin_amdgcn_exp2f(-d1.x), __builtin_amdgcn_exp2f(-d1.y));
                const half2t w2 = __builtin_amdgcn_cvt_pkrtz(
                    __builtin_amdgcn_exp2f(-d2.x), __builtin_amdgcn_exp2f(-d2.y));
                const half2t w3 = __builtin_amdgcn_cvt_pkrtz(
                    __builtin_amdgcn_exp2f(-d3.x), __builtin_amdgcn_exp2f(-d3.y));
                const half8 afrag = (half8){w0.x, w0.y, w1.x, w1.y,
                                            w2.x, w2.y, w3.x, w3.y};
                acc[i] = __builtin_amdgcn_mfma_f32_16x16x32_f16(afrag, bfrag, acc[i], 0, 0, 0);
            }
        }
    }

    // epilogue: lane holds D rows q*4+0..3 (4 m's), col ch. den = col 0.
    float* ob = out + (size_t)b * 9 * M_;
#pragma unroll
    for (int i = 0; i < WM; ++i) {
        const int mg = m_base + (w * WM + i) * 16 + q * 4;
        const f32x4 a = acc[i];
        const int src = lane & 48;                 // lane q*16 holds col 0
        const float d0 = __shfl(a.x, src);
        const float d1 = __shfl(a.y, src);
        const float d2v = __shfl(a.z, src);
        const float d3 = __shfl(a.w, src);
        f32x4 o;
        if (ch == 0) {
            o = a;                                  // density channel
        } else {
            o.x = a.x * __builtin_amdgcn_rcpf(d0 + 1e-5f);
            o.y = a.y * __builtin_amdgcn_rcpf(d1 + 1e-5f);
            o.z = a.z * __builtin_amdgcn_rcpf(d2v + 1e-5f);
            o.w = a.w * __builtin_amdgcn_rcpf(d3 + 1e-5f);
        }
        if (ch < 9)
            *(f32x4*)(ob + (size_t)ch * M_ + mg) = o;
    }
}

extern "C" void kernel_launch(void* const* d_in, const int* in_sizes, int n_in,
                              void* d_out, int out_size, void* d_ws, size_t ws_size,
                              hipStream_t stream) {
    const float* x_c   = (const float*)d_in[0];
    const float* y_c   = (const float*)d_in[1];
    const float* gp    = (const float*)d_in[2];
    const float* sigma = (const float*)d_in[3];
    float* out = (float*)d_out;

    dim3 grid(B_ * MBLOCKS);   // 1024 blocks
    dim3 block(BLK);
    rbf_mfma<<<grid, block, 0, stream>>>(x_c, y_c, gp, sigma, out);
}